// Round 1
// baseline (567.217 us; speedup 1.0000x reference)
//
#include <hip/hip_runtime.h>
#include <math.h>

// Problem constants (B=8, T=4096, D=512, K=4, TOP=2)
#define TOKENS (8 * 4096)
#define DDIM 512
#define TPB 512
#define NBLK 512
#define WAVES_PER_BLK (TPB / 64)

typedef float v4f __attribute__((ext_vector_type(4)));

// R5: true single-pass. R4 still fetched 509 MB (2x ideal): the pass-2 re-read
// missed L2 (per-XCD working set ~4MB == L2 size -> thrash). Structure now:
//   - 1 token per wave per iter: m tile = 4 experts x 2 float4 = 32 VGPRs,
//     held live across logits -> butterfly -> combine. No re-read, ever.
//   - TPB=512: same 64 KiB LDS/block -> still 2 blocks/CU, but 16 waves/CU
//     (50% occupancy) instead of 8. amdgpu_waves_per_eu(4,4) pins the
//     allocator to the 128-reg/4-wave budget that 2x512-thread blocks need.
//   - m loads + out stores nontemporal: zero-reuse streams, keep them from
//     evicting the weight tiles / fighting L2.
__global__ __launch_bounds__(TPB)
__attribute__((amdgpu_waves_per_eu(4, 4)))
void router_kernel(
    const float* __restrict__ m0, const float* __restrict__ m1,
    const float* __restrict__ m2, const float* __restrict__ m3,
    const float* __restrict__ W_top, const float* __restrict__ b_top,
    const float* __restrict__ W_soft, const float* __restrict__ b_soft,
    const float* __restrict__ alpha, float* __restrict__ out)
{
    __shared__ float lt[16 * DDIM];  // W_top  as [k][c][j][dl]  (seg = kc*4+j)
    __shared__ float ls[16 * DDIM];  // W_soft same layout

    const int tid = threadIdx.x;

    // Stage + transpose weights: global n = j*2048 + (d*4 + k), d = c*256+dl
    // -> dst = ((( (k*2+c)*4 + j )) << 8) + dl
    for (int n = tid; n < 8192; n += TPB) {
        int j = n >> 11;
        int e = n & 2047;
        int d = e >> 2;
        int k = e & 3;
        int c = d >> 8;
        int dl = d & 255;
        int dst = ((((k << 1) + c) << 2) + j) * 256 + dl;
        lt[dst] = W_top[n];
        ls[dst] = W_soft[n];
    }

    const float bt0 = b_top[0], bt1 = b_top[1], bt2 = b_top[2], bt3 = b_top[3];
    const float bs0 = b_soft[0], bs1 = b_soft[1], bs2 = b_soft[2], bs3 = b_soft[3];
    const float a = 1.0f / (1.0f + __expf(-alpha[0]));  // sigmoid
    const float na = 1.0f - a;

    __syncthreads();

    const int lane = tid & 63;
    const int wv = tid >> 6;
    const int gw = blockIdx.x * WAVES_PER_BLK + wv;
    const int stride = NBLK * WAVES_PER_BLK;  // tokens per sweep (1/wave)

    const float* __restrict__ ms[4] = {m0, m1, m2, m3};

    for (int t = gw; t < TOKENS; t += stride) {
        const int gbase = t * DDIM + (lane << 2);

        // ---- load the whole token tile once; stays register-resident ----
        v4f r[4][2];
        #pragma unroll
        for (int k = 0; k < 4; ++k) {
            #pragma unroll
            for (int c = 0; c < 2; ++c) {
                r[k][c] = __builtin_nontemporal_load(
                    (const v4f*)(ms[k] + gbase + (c << 8)));
            }
        }

        // ---- logit partial sums from registers ----
        float accT[4] = {0.f, 0.f, 0.f, 0.f};
        float accS[4] = {0.f, 0.f, 0.f, 0.f};
        #pragma unroll
        for (int k = 0; k < 4; ++k) {
            #pragma unroll
            for (int c = 0; c < 2; ++c) {
                const v4f a0 = r[k][c];
                const int segbase = (((k << 1) + c) << 10) + (lane << 2);
                #pragma unroll
                for (int j = 0; j < 4; ++j) {
                    const v4f wt = *(const v4f*)&lt[segbase + (j << 8)];
                    const v4f ws = *(const v4f*)&ls[segbase + (j << 8)];
                    accT[j] += a0.x * wt.x + a0.y * wt.y + a0.z * wt.z + a0.w * wt.w;
                    accS[j] += a0.x * ws.x + a0.y * ws.y + a0.z * ws.z + a0.w * ws.w;
                }
            }
        }

        // ---- butterfly: every lane ends with the full 64-lane sums ----
        #pragma unroll
        for (int j = 0; j < 4; ++j) {
            float vt = accT[j];
            float vs = accS[j];
            #pragma unroll
            for (int mm = 1; mm < 64; mm <<= 1) {
                vt += __shfl_xor(vt, mm, 64);
                vs += __shfl_xor(vs, mm, 64);
            }
            accT[j] = vt;
            accS[j] = vs;
        }

        // ---- routing weights ----
        const float l0 = accT[0] + bt0, l1 = accT[1] + bt1;
        const float l2 = accT[2] + bt2, l3 = accT[3] + bt3;

        // top-1 (strict > keeps lower index on ties, matching jax.lax.top_k)
        int i1 = 0; float v1 = l0;
        if (l1 > v1) { v1 = l1; i1 = 1; }
        if (l2 > v1) { v1 = l2; i1 = 2; }
        if (l3 > v1) { v1 = l3; i1 = 3; }
        // top-2 among the rest
        float v2 = -INFINITY; int i2 = 0;
        if (i1 != 0)            { v2 = l0; i2 = 0; }
        if (i1 != 1 && l1 > v2) { v2 = l1; i2 = 1; }
        if (i1 != 2 && l2 > v2) { v2 = l2; i2 = 2; }
        if (i1 != 3 && l3 > v2) { v2 = l3; i2 = 3; }

        const float eh = __expf(v2 - v1);       // v2 <= v1: stable
        const float p1 = 1.0f / (1.0f + eh);
        const float p2 = eh * p1;

        const float x0 = accS[0] + bs0, x1 = accS[1] + bs1;
        const float x2 = accS[2] + bs2, x3 = accS[3] + bs3;
        const float mx = fmaxf(fmaxf(x0, x1), fmaxf(x2, x3));
        const float e0 = __expf(x0 - mx), e1 = __expf(x1 - mx);
        const float e2 = __expf(x2 - mx), e3 = __expf(x3 - mx);
        const float inv = 1.0f / (e0 + e1 + e2 + e3);

        float w0 = na * e0 * inv;
        float w1 = na * e1 * inv;
        float w2 = na * e2 * inv;
        float w3 = na * e3 * inv;
        const float ap1 = a * p1, ap2 = a * p2;
        w0 += (i1 == 0 ? ap1 : 0.0f) + (i2 == 0 ? ap2 : 0.0f);
        w1 += (i1 == 1 ? ap1 : 0.0f) + (i2 == 1 ? ap2 : 0.0f);
        w2 += (i1 == 2 ? ap1 : 0.0f) + (i2 == 2 ? ap2 : 0.0f);
        w3 += (i1 == 3 ? ap1 : 0.0f) + (i2 == 3 ? ap2 : 0.0f);

        // ---- combine straight from the register tile; stream the store ----
        #pragma unroll
        for (int c = 0; c < 2; ++c) {
            v4f o = r[0][c] * w0 + r[1][c] * w1 + r[2][c] * w2 + r[3][c] * w3;
            __builtin_nontemporal_store(o, (v4f*)(out + gbase + (c << 8)));
        }
    }
}

extern "C" void kernel_launch(void* const* d_in, const int* in_sizes, int n_in,
                              void* d_out, int out_size, void* d_ws, size_t ws_size,
                              hipStream_t stream) {
    const float* m0     = (const float*)d_in[0];
    const float* m1     = (const float*)d_in[1];
    const float* m2     = (const float*)d_in[2];
    const float* m3     = (const float*)d_in[3];
    const float* W_top  = (const float*)d_in[4];
    const float* b_top  = (const float*)d_in[5];
    const float* W_soft = (const float*)d_in[6];
    const float* b_soft = (const float*)d_in[7];
    const float* alpha  = (const float*)d_in[8];
    float* outp = (float*)d_out;

    router_kernel<<<NBLK, TPB, 0, stream>>>(m0, m1, m2, m3, W_top, b_top,
                                            W_soft, b_soft, alpha, outp);
}

// Round 3
// 465.591 us; speedup vs baseline: 1.2183x; 1.2183x over previous
//
#include <hip/hip_runtime.h>
#include <math.h>

// Problem constants (B=8, T=4096, D=512, K=4, TOP=2)
#define TOKENS (8 * 4096)
#define DDIM 512
#define TPB 256
#define NBLK 512
#define WAVES_PER_BLK (TPB / 64)

typedef float v4f __attribute__((ext_vector_type(4)));

// R7 == R6 resubmitted (R6 bench failed on container infra, not kernel).
// R6: single-pass with R4's PROVEN register configuration.
// R5 post-mortem: waves_per_eu(4,4) @ TPB=512 made the allocator squeeze to
// 64 VGPRs -> the "register-resident" tile was spilled/rematerialized
// (FETCH 1.19 GB = ~4.5x ideal) and nt stores inflated WRITE 5x. Occupancy
// doubled but BW barely moved -> occupancy was not the constraint; traffic is.
// R6 shape:
//   - TPB=256 + waves_per_eu(2,2): R4 measured VGPR=128, zero spill. 256-reg
//     budget, ~150 live regs needed here -> comfortable.
//   - 2 tokens/wave, SINGLE pass: m tile (64 regs) loaded once, consumed for
//     logits AND combine from registers. Read traffic = 256 MB by construction.
//   - each LDS weight ds_read_b128 feeds both tokens -> 32 LDS reads/token
//     (halved), shorter per-token serial chain.
//   - 16 outstanding global loads per wave -> 2x MLP at same occupancy.
//   - plain cached loads/stores (no nontemporal anywhere).
__global__ __launch_bounds__(TPB)
__attribute__((amdgpu_waves_per_eu(2, 2)))
void router_kernel(
    const float* __restrict__ m0, const float* __restrict__ m1,
    const float* __restrict__ m2, const float* __restrict__ m3,
    const float* __restrict__ W_top, const float* __restrict__ b_top,
    const float* __restrict__ W_soft, const float* __restrict__ b_soft,
    const float* __restrict__ alpha, float* __restrict__ out)
{
    __shared__ float lt[16 * DDIM];  // W_top  as [k][c][j][dl]  (seg = kc*4+j)
    __shared__ float ls[16 * DDIM];  // W_soft same layout

    const int tid = threadIdx.x;

    // Stage + transpose weights: global n = j*2048 + (d*4 + k), d = c*256+dl
    // -> dst = ((( (k*2+c)*4 + j )) << 8) + dl
    for (int n = tid; n < 8192; n += TPB) {
        int j = n >> 11;
        int e = n & 2047;
        int d = e >> 2;
        int k = e & 3;
        int c = d >> 8;
        int dl = d & 255;
        int dst = ((((k << 1) + c) << 2) + j) * 256 + dl;
        lt[dst] = W_top[n];
        ls[dst] = W_soft[n];
    }

    const float bt0 = b_top[0], bt1 = b_top[1], bt2 = b_top[2], bt3 = b_top[3];
    const float bs0 = b_soft[0], bs1 = b_soft[1], bs2 = b_soft[2], bs3 = b_soft[3];
    const float a = 1.0f / (1.0f + __expf(-alpha[0]));  // sigmoid
    const float na = 1.0f - a;

    __syncthreads();

    const int lane = tid & 63;
    const int wv = tid >> 6;
    const int gw = blockIdx.x * WAVES_PER_BLK + wv;
    const int stride = NBLK * WAVES_PER_BLK * 2;  // tokens per sweep (2/wave)

    const float* __restrict__ ms[4] = {m0, m1, m2, m3};

    for (int t0 = gw * 2; t0 < TOKENS; t0 += stride) {
        // ---- load both tokens' full tiles once; register-resident ----
        v4f r[2][4][2];
        #pragma unroll
        for (int k = 0; k < 4; ++k) {
            #pragma unroll
            for (int tk = 0; tk < 2; ++tk) {
                const int goff = (t0 + tk) * DDIM + (lane << 2);
                #pragma unroll
                for (int c = 0; c < 2; ++c) {
                    r[tk][k][c] = *(const v4f*)(ms[k] + goff + (c << 8));
                }
            }
        }

        // ---- logit partial sums; each LDS read feeds both tokens ----
        float accT[2][4] = {{0, 0, 0, 0}, {0, 0, 0, 0}};
        float accS[2][4] = {{0, 0, 0, 0}, {0, 0, 0, 0}};
        #pragma unroll
        for (int k = 0; k < 4; ++k) {
            #pragma unroll
            for (int c = 0; c < 2; ++c) {
                const int segbase = (((k << 1) + c) << 10) + (lane << 2);
                #pragma unroll
                for (int j = 0; j < 4; ++j) {
                    const v4f wt = *(const v4f*)&lt[segbase + (j << 8)];
                    const v4f ws = *(const v4f*)&ls[segbase + (j << 8)];
                    #pragma unroll
                    for (int tk = 0; tk < 2; ++tk) {
                        const v4f a0 = r[tk][k][c];
                        accT[tk][j] += a0.x * wt.x + a0.y * wt.y + a0.z * wt.z + a0.w * wt.w;
                        accS[tk][j] += a0.x * ws.x + a0.y * ws.y + a0.z * ws.z + a0.w * ws.w;
                    }
                }
            }
        }

        // ---- butterfly: every lane ends with the full 64-lane sums ----
        #pragma unroll
        for (int tk = 0; tk < 2; ++tk) {
            #pragma unroll
            for (int j = 0; j < 4; ++j) {
                float vt = accT[tk][j];
                float vs = accS[tk][j];
                #pragma unroll
                for (int mm = 1; mm < 64; mm <<= 1) {
                    vt += __shfl_xor(vt, mm, 64);
                    vs += __shfl_xor(vs, mm, 64);
                }
                accT[tk][j] = vt;
                accS[tk][j] = vs;
            }
        }

        // ---- routing weights + combine from the register tile ----
        #pragma unroll
        for (int tk = 0; tk < 2; ++tk) {
            const float l0 = accT[tk][0] + bt0, l1 = accT[tk][1] + bt1;
            const float l2 = accT[tk][2] + bt2, l3 = accT[tk][3] + bt3;

            // top-1 (strict > keeps lower index on ties, matching jax.lax.top_k)
            int i1 = 0; float v1 = l0;
            if (l1 > v1) { v1 = l1; i1 = 1; }
            if (l2 > v1) { v1 = l2; i1 = 2; }
            if (l3 > v1) { v1 = l3; i1 = 3; }
            // top-2 among the rest
            float v2 = -INFINITY; int i2 = 0;
            if (i1 != 0)            { v2 = l0; i2 = 0; }
            if (i1 != 1 && l1 > v2) { v2 = l1; i2 = 1; }
            if (i1 != 2 && l2 > v2) { v2 = l2; i2 = 2; }
            if (i1 != 3 && l3 > v2) { v2 = l3; i2 = 3; }

            const float eh = __expf(v2 - v1);       // v2 <= v1: stable
            const float p1 = 1.0f / (1.0f + eh);
            const float p2 = eh * p1;

            const float x0 = accS[tk][0] + bs0, x1 = accS[tk][1] + bs1;
            const float x2 = accS[tk][2] + bs2, x3 = accS[tk][3] + bs3;
            const float mx = fmaxf(fmaxf(x0, x1), fmaxf(x2, x3));
            const float e0 = __expf(x0 - mx), e1 = __expf(x1 - mx);
            const float e2 = __expf(x2 - mx), e3 = __expf(x3 - mx);
            const float inv = 1.0f / (e0 + e1 + e2 + e3);

            float w0 = na * e0 * inv;
            float w1 = na * e1 * inv;
            float w2 = na * e2 * inv;
            float w3 = na * e3 * inv;
            const float ap1 = a * p1, ap2 = a * p2;
            w0 += (i1 == 0 ? ap1 : 0.0f) + (i2 == 0 ? ap2 : 0.0f);
            w1 += (i1 == 1 ? ap1 : 0.0f) + (i2 == 1 ? ap2 : 0.0f);
            w2 += (i1 == 2 ? ap1 : 0.0f) + (i2 == 2 ? ap2 : 0.0f);
            w3 += (i1 == 3 ? ap1 : 0.0f) + (i2 == 3 ? ap2 : 0.0f);

            const int base = (t0 + tk) * DDIM + (lane << 2);
            #pragma unroll
            for (int c = 0; c < 2; ++c) {
                v4f o = r[tk][0][c] * w0 + r[tk][1][c] * w1
                      + r[tk][2][c] * w2 + r[tk][3][c] * w3;
                *(v4f*)(out + base + (c << 8)) = o;
            }
        }
    }
}

extern "C" void kernel_launch(void* const* d_in, const int* in_sizes, int n_in,
                              void* d_out, int out_size, void* d_ws, size_t ws_size,
                              hipStream_t stream) {
    const float* m0     = (const float*)d_in[0];
    const float* m1     = (const float*)d_in[1];
    const float* m2     = (const float*)d_in[2];
    const float* m3     = (const float*)d_in[3];
    const float* W_top  = (const float*)d_in[4];
    const float* b_top  = (const float*)d_in[5];
    const float* W_soft = (const float*)d_in[6];
    const float* b_soft = (const float*)d_in[7];
    const float* alpha  = (const float*)d_in[8];
    float* outp = (float*)d_out;

    router_kernel<<<NBLK, TPB, 0, stream>>>(m0, m1, m2, m3, W_top, b_top,
                                            W_soft, b_soft, alpha, outp);
}

// Round 4
// 365.039 us; speedup vs baseline: 1.5539x; 1.2755x over previous
//
#include <hip/hip_runtime.h>
#include <math.h>

// Problem constants (B=8, T=4096, D=512, K=4, TOP=2)
#define TOKENS (8 * 4096)
#define DDIM 512
#define TPB 256
#define NBLK 512
#define WAVES_PER_BLK (TPB / 64)

typedef float v4f __attribute__((ext_vector_type(4)));

// R8: single-pass that FITS the 128-reg allocation.
// R7 post-mortem: 2-token tile (64 regs) + accs + temps ~150 live > the 128
// VGPRs the allocator pins at (3rd time observed) -> half the tile spilled
// (WRITE 200MB = 64 ideal + ~137 spill) and dur regressed 205->300us.
// R8 shape:
//   - 1 token/wave (R5's dataflow, which PASSED): tile = 8 v4f = 32 regs,
//     ~80 live max. No spill possible under the 128-reg budget.
//   - TPB=256 + waves_per_eu(2,2), plain cached loads/stores (R4-proven).
//   - pack-reduce allreduce: 3 select+shfl fold levels (8 vals -> 1/lane,
//     idx=lane&7), 3 xor levels for the 64-lane sum, 8 uniform broadcasts.
//     7 chained shfls instead of 48 -> ~4.5x shorter serial DS chain.
__global__ __launch_bounds__(TPB)
__attribute__((amdgpu_waves_per_eu(2, 2)))
void router_kernel(
    const float* __restrict__ m0, const float* __restrict__ m1,
    const float* __restrict__ m2, const float* __restrict__ m3,
    const float* __restrict__ W_top, const float* __restrict__ b_top,
    const float* __restrict__ W_soft, const float* __restrict__ b_soft,
    const float* __restrict__ alpha, float* __restrict__ out)
{
    __shared__ float lt[16 * DDIM];  // W_top  as [k][c][j][dl]  (seg = kc*4+j)
    __shared__ float ls[16 * DDIM];  // W_soft same layout

    const int tid = threadIdx.x;

    // Stage + transpose weights: global n = j*2048 + (d*4 + k), d = c*256+dl
    // -> dst = ((( (k*2+c)*4 + j )) << 8) + dl
    for (int n = tid; n < 8192; n += TPB) {
        int j = n >> 11;
        int e = n & 2047;
        int d = e >> 2;
        int k = e & 3;
        int c = d >> 8;
        int dl = d & 255;
        int dst = ((((k << 1) + c) << 2) + j) * 256 + dl;
        lt[dst] = W_top[n];
        ls[dst] = W_soft[n];
    }

    const float bt0 = b_top[0], bt1 = b_top[1], bt2 = b_top[2], bt3 = b_top[3];
    const float bs0 = b_soft[0], bs1 = b_soft[1], bs2 = b_soft[2], bs3 = b_soft[3];
    const float a = 1.0f / (1.0f + __expf(-alpha[0]));  // sigmoid
    const float na = 1.0f - a;

    __syncthreads();

    const int lane = tid & 63;
    const int wv = tid >> 6;
    const int gw = blockIdx.x * WAVES_PER_BLK + wv;
    const int stride = NBLK * WAVES_PER_BLK;  // tokens per sweep (1/wave)

    const float* __restrict__ ms[4] = {m0, m1, m2, m3};

    const int lb1 = lane & 1, lb2 = lane & 2, lb4 = lane & 4;

    for (int t = gw; t < TOKENS; t += stride) {
        const int gbase = t * DDIM + (lane << 2);

        // ---- load the token tile once; register-resident (32 regs) ----
        v4f r[4][2];
        #pragma unroll
        for (int k = 0; k < 4; ++k) {
            #pragma unroll
            for (int c = 0; c < 2; ++c) {
                r[k][c] = *(const v4f*)(ms[k] + gbase + (c << 8));
            }
        }

        // ---- logit partial sums from registers ----
        // acc[0..3] = top logits, acc[4..7] = soft logits
        float acc[8] = {0.f, 0.f, 0.f, 0.f, 0.f, 0.f, 0.f, 0.f};
        #pragma unroll
        for (int k = 0; k < 4; ++k) {
            #pragma unroll
            for (int c = 0; c < 2; ++c) {
                const v4f a0 = r[k][c];
                const int segbase = (((k << 1) + c) << 10) + (lane << 2);
                #pragma unroll
                for (int j = 0; j < 4; ++j) {
                    const v4f wt = *(const v4f*)&lt[segbase + (j << 8)];
                    const v4f ws = *(const v4f*)&ls[segbase + (j << 8)];
                    acc[j]     += a0.x * wt.x + a0.y * wt.y + a0.z * wt.z + a0.w * wt.w;
                    acc[4 + j] += a0.x * ws.x + a0.y * ws.y + a0.z * ws.z + a0.w * ws.w;
                }
            }
        }

        // ---- pack-reduce allreduce of 8 values over 64 lanes ----
        // fold level 1 (xor 1): pairs (0,1),(2,3),(4,5),(6,7)
        float k0 = lb1 ? acc[1] : acc[0];
        float s0 = lb1 ? acc[0] : acc[1];
        float k1 = lb1 ? acc[3] : acc[2];
        float s1 = lb1 ? acc[2] : acc[3];
        float k2 = lb1 ? acc[5] : acc[4];
        float s2 = lb1 ? acc[4] : acc[5];
        float k3 = lb1 ? acc[7] : acc[6];
        float s3 = lb1 ? acc[6] : acc[7];
        k0 += __shfl_xor(s0, 1, 64);
        k1 += __shfl_xor(s1, 1, 64);
        k2 += __shfl_xor(s2, 1, 64);
        k3 += __shfl_xor(s3, 1, 64);
        // fold level 2 (xor 2): (k0,k1) -> values 0-3; (k2,k3) -> values 4-7
        float q0 = lb2 ? k1 : k0;
        float u0 = lb2 ? k0 : k1;
        float q1 = lb2 ? k3 : k2;
        float u1 = lb2 ? k2 : k3;
        q0 += __shfl_xor(u0, 2, 64);
        q1 += __shfl_xor(u1, 2, 64);
        // fold level 3 (xor 4): lane now holds value (lane&7), partial over
        // its 8-lane cohort
        float p = lb4 ? q1 : q0;
        float u = lb4 ? q0 : q1;
        p += __shfl_xor(u, 4, 64);
        // finish the 64-lane sum (same value index at lane^8/16/32)
        p += __shfl_xor(p, 8, 64);
        p += __shfl_xor(p, 16, 64);
        p += __shfl_xor(p, 32, 64);
        // broadcast: lane i (i<8) holds the full sum of value i
        float red[8];
        #pragma unroll
        for (int i = 0; i < 8; ++i) red[i] = __shfl(p, i, 64);

        // ---- routing weights ----
        const float l0 = red[0] + bt0, l1 = red[1] + bt1;
        const float l2 = red[2] + bt2, l3 = red[3] + bt3;

        // top-1 (strict > keeps lower index on ties, matching jax.lax.top_k)
        int i1 = 0; float v1 = l0;
        if (l1 > v1) { v1 = l1; i1 = 1; }
        if (l2 > v1) { v1 = l2; i1 = 2; }
        if (l3 > v1) { v1 = l3; i1 = 3; }
        // top-2 among the rest
        float v2 = -INFINITY; int i2 = 0;
        if (i1 != 0)            { v2 = l0; i2 = 0; }
        if (i1 != 1 && l1 > v2) { v2 = l1; i2 = 1; }
        if (i1 != 2 && l2 > v2) { v2 = l2; i2 = 2; }
        if (i1 != 3 && l3 > v2) { v2 = l3; i2 = 3; }

        const float eh = __expf(v2 - v1);       // v2 <= v1: stable
        const float p1 = 1.0f / (1.0f + eh);
        const float p2 = eh * p1;

        const float x0 = red[4] + bs0, x1 = red[5] + bs1;
        const float x2 = red[6] + bs2, x3 = red[7] + bs3;
        const float mx = fmaxf(fmaxf(x0, x1), fmaxf(x2, x3));
        const float e0 = __expf(x0 - mx), e1 = __expf(x1 - mx);
        const float e2 = __expf(x2 - mx), e3 = __expf(x3 - mx);
        const float inv = 1.0f / (e0 + e1 + e2 + e3);

        float w0 = na * e0 * inv;
        float w1 = na * e1 * inv;
        float w2 = na * e2 * inv;
        float w3 = na * e3 * inv;
        const float ap1 = a * p1, ap2 = a * p2;
        w0 += (i1 == 0 ? ap1 : 0.0f) + (i2 == 0 ? ap2 : 0.0f);
        w1 += (i1 == 1 ? ap1 : 0.0f) + (i2 == 1 ? ap2 : 0.0f);
        w2 += (i1 == 2 ? ap1 : 0.0f) + (i2 == 2 ? ap2 : 0.0f);
        w3 += (i1 == 3 ? ap1 : 0.0f) + (i2 == 3 ? ap2 : 0.0f);

        // ---- combine straight from the register tile ----
        #pragma unroll
        for (int c = 0; c < 2; ++c) {
            v4f o = r[0][c] * w0 + r[1][c] * w1 + r[2][c] * w2 + r[3][c] * w3;
            *(v4f*)(out + gbase + (c << 8)) = o;
        }
    }
}

extern "C" void kernel_launch(void* const* d_in, const int* in_sizes, int n_in,
                              void* d_out, int out_size, void* d_ws, size_t ws_size,
                              hipStream_t stream) {
    const float* m0     = (const float*)d_in[0];
    const float* m1     = (const float*)d_in[1];
    const float* m2     = (const float*)d_in[2];
    const float* m3     = (const float*)d_in[3];
    const float* W_top  = (const float*)d_in[4];
    const float* b_top  = (const float*)d_in[5];
    const float* W_soft = (const float*)d_in[6];
    const float* b_soft = (const float*)d_in[7];
    const float* alpha  = (const float*)d_in[8];
    float* outp = (float*)d_out;

    router_kernel<<<NBLK, TPB, 0, stream>>>(m0, m1, m2, m3, W_top, b_top,
                                            W_soft, b_soft, alpha, outp);
}